// Round 5
// baseline (1926.037 us; speedup 1.0000x reference)
//
#include <hip/hip_runtime.h>
#include <stdint.h>

// HeadwiseLowRankModule: out = blockdiag-GEMM(GEMM(hidden, VT^T), U^T), f32 I/O.
// Inputs converted to bf16 once. GEMM1: 256x256-tile 8-phase deep pipeline
// (T2 swizzle + counted vmcnt + setprio), constexpr strides.
// launch_bounds(512, 1): 128KiB LDS already caps at 1 wg/CU (2 waves/SIMD);
// ",2" was read as 2 wg/CU -> 128-VGPR cap -> massive spills (r3/r4 evidence).
// GEMM2: proven m97 128x128 kernel.

typedef short  bf16x8  __attribute__((ext_vector_type(8)));
typedef float  f32x4   __attribute__((ext_vector_type(4)));
typedef ushort ushort8 __attribute__((ext_vector_type(8)));
typedef float  flt4    __attribute__((ext_vector_type(4)));

__device__ __forceinline__ void gload_lds16(const ushort* g, ushort* l) {
    __builtin_amdgcn_global_load_lds(
        (const __attribute__((address_space(1))) uint32_t*)g,
        (__attribute__((address_space(3))) uint32_t*)l, 16, 0, 0);
}

__device__ __forceinline__ ushort f2bf(float f) {
    union { float f; uint32_t u; } c; c.f = f;
    uint32_t u = c.u;
    uint32_t r = (u + 0x7FFFu + ((u >> 16) & 1u)) >> 16;  // RNE
    return (ushort)r;
}

__device__ __forceinline__ void cfence() { asm volatile("" ::: "memory"); }

template<int N> __device__ __forceinline__ void vwait() {
    if constexpr (N == 8)      asm volatile("s_waitcnt vmcnt(8)" ::: "memory");
    else if constexpr (N == 4) asm volatile("s_waitcnt vmcnt(4)" ::: "memory");
    else if constexpr (N == 2) asm volatile("s_waitcnt vmcnt(2)" ::: "memory");
    else if constexpr (N == 0) asm volatile("s_waitcnt vmcnt(0)" ::: "memory");
    // N < 0: no wait
}

// ---- f32 -> bf16 conversion ----
__global__ __launch_bounds__(256) void f32_to_bf16_kernel(
    const float* __restrict__ in, ushort* __restrict__ out, long n8)
{
    const long stride = (long)gridDim.x * blockDim.x;
    for (long i = (long)blockIdx.x * blockDim.x + threadIdx.x; i < n8; i += stride) {
        flt4 a = ((const flt4*)in)[2 * i];
        flt4 b = ((const flt4*)in)[2 * i + 1];
        ushort8 o;
        o[0] = f2bf(a[0]); o[1] = f2bf(a[1]); o[2] = f2bf(a[2]); o[3] = f2bf(a[3]);
        o[4] = f2bf(b[0]); o[5] = f2bf(b[1]); o[6] = f2bf(b[2]); o[7] = f2bf(b[3]);
        ((ushort8*)out)[i] = o;
    }
}

// =====================================================================
// GEMM1: 256x256 tile, BK=64, 8 waves (2Mx4N), 8-phase pipeline.
// Regions: R1=A rows[0,128), R3=A[128,256), R2=B[0,128), R4=B[128,256).
// Tile t phases (mg,ng)=(0,0),(0,1),(1,0),(1,1).
// Stage stream: R1(x)@4x, R2@4x+1, R4@4x+2, R3@4x+3.
// Tile t: p0 stages R4(t+1)->other, p1 R3(t+1)->other, p2 R1(t+2)->cur,
// p3 R2(t+2)->cur. Uniform vmcnt(8); tail drains 4 -> 2 -> 0.
// Swizzle: byteOff ^= (row&7)<<4.
// =====================================================================

#define ARD(BUF, MG, MF, KK) \
    (*(const bf16x8*)&(BUF)[(((MG)*128 + wr*64 + (MF)*16 + l15) * 64) + \
                            (((((KK)<<2) | lq) ^ l7) << 3)])
#define BRD(BUF, NG, NF, KK) \
    (*(const bf16x8*)&(BUF)[(((NG)*128 + wc*32 + (NF)*16 + l15) * 64) + \
                            (((((KK)<<2) | lq) ^ l7) << 3)])

#define STAGE_A(H, KT, ABUF) do { \
    const ushort* _g = aSt + (H)*128*LDA + (KT)*64; \
    gload_lds16(_g,            (ABUF) + (H)*8192 + ldsoff0); \
    gload_lds16(_g + 64*LDA,   (ABUF) + (H)*8192 + ldsoff1); \
} while (0)
#define STAGE_B(H, KT, BBUF) do { \
    const ushort* _g = bSt + (H)*128*LDB + (KT)*64; \
    gload_lds16(_g,            (BBUF) + (H)*8192 + ldsoff0); \
    gload_lds16(_g + 64*LDB,   (BBUF) + (H)*8192 + ldsoff1); \
} while (0)

#define MFMA_Q(MG, NG, BB) \
    _Pragma("unroll") \
    for (int mf = 0; mf < 4; ++mf) \
    _Pragma("unroll") \
    for (int nf = 0; nf < 2; ++nf) \
    _Pragma("unroll") \
    for (int kk = 0; kk < 2; ++kk) \
        acc[(MG)*4+mf][(NG)*2+nf] = __builtin_amdgcn_mfma_f32_16x16x32_bf16( \
            a[mf][kk], BB[nf][kk], acc[(MG)*4+mf][(NG)*2+nf], 0, 0, 0);

#define TILE_BODY(CA, CB, OA, OB, KT1, KT2, S0, S1, S2, S3, W0, W1, W2, W3) do { \
    /* phase 0: read A mg0 (8) + B ng0 (4); stage R4(KT1)->other B */ \
    _Pragma("unroll") \
    for (int mf = 0; mf < 4; ++mf) { a[mf][0] = ARD(CA,0,mf,0); a[mf][1] = ARD(CA,0,mf,1); } \
    _Pragma("unroll") \
    for (int nf = 0; nf < 2; ++nf) { b0[nf][0] = BRD(CB,0,nf,0); b0[nf][1] = BRD(CB,0,nf,1); } \
    if (S0) { STAGE_B(1, KT1, OB); } \
    __builtin_amdgcn_s_barrier(); \
    __builtin_amdgcn_s_setprio(1); \
    MFMA_Q(0, 0, b0); \
    __builtin_amdgcn_s_setprio(0); \
    vwait<W0>(); \
    __builtin_amdgcn_s_barrier(); \
    cfence(); \
    /* phase 1: read B ng1 (4); stage R3(KT1)->other A */ \
    _Pragma("unroll") \
    for (int nf = 0; nf < 2; ++nf) { b1[nf][0] = BRD(CB,1,nf,0); b1[nf][1] = BRD(CB,1,nf,1); } \
    if (S1) { STAGE_A(1, KT1, OA); } \
    __builtin_amdgcn_s_barrier(); \
    __builtin_amdgcn_s_setprio(1); \
    MFMA_Q(0, 1, b1); \
    __builtin_amdgcn_s_setprio(0); \
    vwait<W1>(); \
    __builtin_amdgcn_s_barrier(); \
    cfence(); \
    /* phase 2: read A mg1 (8); stage R1(KT2)->cur A (free after p0) */ \
    _Pragma("unroll") \
    for (int mf = 0; mf < 4; ++mf) { a[mf][0] = ARD(CA,1,mf,0); a[mf][1] = ARD(CA,1,mf,1); } \
    if (S2) { STAGE_A(0, KT2, CA); } \
    __builtin_amdgcn_s_barrier(); \
    __builtin_amdgcn_s_setprio(1); \
    MFMA_Q(1, 0, b0); \
    __builtin_amdgcn_s_setprio(0); \
    vwait<W2>(); \
    __builtin_amdgcn_s_barrier(); \
    cfence(); \
    /* phase 3: no reads; stage R2(KT2)->cur B (free after p0) */ \
    if (S3) { STAGE_B(0, KT2, CB); } \
    __builtin_amdgcn_s_barrier(); \
    __builtin_amdgcn_s_setprio(1); \
    MFMA_Q(1, 1, b1); \
    __builtin_amdgcn_s_setprio(0); \
    vwait<W3>(); \
    __builtin_amdgcn_s_barrier(); \
    cfence(); \
} while (0)

template<int LDA, int LDB, int LDC, int KDIM>
__global__ __launch_bounds__(512, 1) void gemm256_bf16(
    const ushort* __restrict__ A, const ushort* __restrict__ B,
    ushort* __restrict__ C)
{
    extern __shared__ ushort lds[];
    ushort* A0 = lds;              // buf0 A: 256x64 elems (32 KiB)
    ushort* B0 = lds + 16384;
    ushort* A1 = lds + 32768;
    ushort* B1 = lds + 49152;

    const int tid  = threadIdx.x;
    const int lane = tid & 63;
    const int wave = tid >> 6;       // 0..7
    const int wr = wave >> 2;        // 0..1
    const int wc = wave & 3;         // 0..3

    // XCD-locality mapping: x (N-tile) fastest -> each XCD keeps one VT panel
    const int bx = blockIdx.x & 7;
    const int by = blockIdx.x >> 3;
    const int row0 = by * 256;
    const int col0 = bx * 256;

    const int l15 = lane & 15;
    const int lq  = lane >> 4;       // 0..3
    const int l7  = lane & 7;

    // staging constants: linear idx = j*512 + tid; row = idx>>3; chunk swizzle
    const int srow = tid >> 3;                              // j=0 row (j=1: +64)
    const int scsw = (((tid & 7) ^ (srow & 7)) << 3);       // swizzled col (elems)
    const int ldsoff0 = (wave * 64) * 8;                    // wave-uniform dests
    const int ldsoff1 = (512 + wave * 64) * 8;

    // hoisted per-thread global staging bases
    const ushort* aSt = A + (size_t)(row0 + srow) * LDA + scsw;
    const ushort* bSt = B + (size_t)(col0 + srow) * LDB + scsw;

    f32x4 acc[8][4] = {};
    bf16x8 a[4][2], b0[2][2], b1[2][2];

    constexpr int nkt = KDIM >> 6;

    // Prologue: stage R1(0),R2(0),R4(0),R3(0),R1(1),R2(1)
    STAGE_A(0, 0, A0);
    STAGE_B(0, 0, B0);
    STAGE_B(1, 0, B0);
    STAGE_A(1, 0, A0);
    STAGE_A(0, 1, A1);
    STAGE_B(0, 1, B1);
    vwait<8>();                       // R1(0),R2(0) complete
    __builtin_amdgcn_s_barrier();
    cfence();

    for (int t = 0; t < nkt - 2; ++t) {
        if ((t & 1) == 0) TILE_BODY(A0, B0, A1, B1, t+1, t+2, 1,1,1,1, 8,8,8,8);
        else              TILE_BODY(A1, B1, A0, B0, t+1, t+2, 1,1,1,1, 8,8,8,8);
    }
    {   // tail tile nkt-2: stage only R4/R3(nkt-1); drain to 4
        const int t = nkt - 2;
        if ((t & 1) == 0) TILE_BODY(A0, B0, A1, B1, t+1, 0, 1,1,0,0, 8,8,8,4);
        else              TILE_BODY(A1, B1, A0, B0, t+1, 0, 1,1,0,0, 8,8,8,4);
    }
    {   // tail tile nkt-1: no staging; drain 2 -> 0
        const int t = nkt - 1;
        if ((t & 1) == 0) TILE_BODY(A0, B0, A1, B1, 0, 0, 0,0,0,0, 2,0,-1,-1);
        else              TILE_BODY(A1, B1, A0, B0, 0, 0, 0,0,0,0, 2,0,-1,-1);
    }

    // Epilogue: C/D layout col = lane&15, row = (lane>>4)*4 + reg
    #pragma unroll
    for (int mg = 0; mg < 2; ++mg)
    #pragma unroll
    for (int mf = 0; mf < 4; ++mf) {
        const int rowb = row0 + mg*128 + wr*64 + mf*16 + lq*4;
        #pragma unroll
        for (int r = 0; r < 4; ++r) {
            ushort* crow = C + (size_t)(rowb + r) * LDC;
            #pragma unroll
            for (int ng = 0; ng < 2; ++ng)
            #pragma unroll
            for (int nf = 0; nf < 2; ++nf)
                crow[col0 + ng*128 + wc*32 + nf*16 + l15] =
                    f2bf(acc[mg*4+mf][ng*2+nf][r]);
        }
    }
}

// ---- store helpers ----
__device__ __forceinline__ void store_out(ushort* p, float v) { *p = f2bf(v); }
__device__ __forceinline__ void store_out(float*  p, float v) { *p = v; }

// GEMM2: proven m97-style 128x128 kernel (block-diagonal via blockIdx.z)
template <typename TOUT>
__global__ __launch_bounds__(256) void gemm_bt_kernel(
    const ushort* __restrict__ A,
    const ushort* __restrict__ B,
    TOUT* __restrict__ C,
    int lda, int ldb, int ldc, int K,
    long aOffZ, long bOffZ, long cOffZ)
{
    A += (size_t)blockIdx.z * aOffZ;
    B += (size_t)blockIdx.z * bOffZ;
    C += (size_t)blockIdx.z * cOffZ;

    __shared__ ushort As[128 * 64];
    __shared__ ushort Bs[128 * 64];

    const int tid  = threadIdx.x;
    const int lane = tid & 63;
    const int wave = tid >> 6;

    const int row0 = blockIdx.y * 128;
    const int col0 = blockIdx.x * 128;

    const int wr = wave >> 1;
    const int wc = wave & 1;

    const int l15    = lane & 15;
    const int lq     = lane >> 4;
    const int lrow   = lane >> 3;
    const int lchunk = lane & 7;

    f32x4 acc[4][4] = {};

    const ushort* aPtr = A + (size_t)(row0 + wave * 32 + lrow) * lda + lchunk * 8;
    const ushort* bPtr = B + (size_t)(col0 + wave * 32 + lrow) * ldb + lchunk * 8;

    const int nkt = K / 64;
    for (int kt = 0; kt < nkt; ++kt) {
        const int kOff = kt * 64;
        __syncthreads();
        #pragma unroll
        for (int i = 0; i < 4; ++i) {
            gload_lds16(aPtr + (size_t)i * 8 * lda + kOff, As + (wave * 4 + i) * 512);
            gload_lds16(bPtr + (size_t)i * 8 * ldb + kOff, Bs + (wave * 4 + i) * 512);
        }
        __syncthreads();

        #pragma unroll
        for (int kk = 0; kk < 2; ++kk) {
            bf16x8 af[4], bfr[4];
            #pragma unroll
            for (int m = 0; m < 4; ++m)
                af[m] = *(const bf16x8*)&As[(wr * 64 + m * 16 + l15) * 64 + kk * 32 + lq * 8];
            #pragma unroll
            for (int n = 0; n < 4; ++n)
                bfr[n] = *(const bf16x8*)&Bs[(wc * 64 + n * 16 + l15) * 64 + kk * 32 + lq * 8];
            #pragma unroll
            for (int m = 0; m < 4; ++m)
                #pragma unroll
                for (int n = 0; n < 4; ++n)
                    acc[m][n] = __builtin_amdgcn_mfma_f32_16x16x32_bf16(
                        af[m], bfr[n], acc[m][n], 0, 0, 0);
        }
    }

    #pragma unroll
    for (int m = 0; m < 4; ++m) {
        #pragma unroll
        for (int r = 0; r < 4; ++r) {
            const size_t row = (size_t)(row0 + wr * 64 + m * 16 + lq * 4 + r);
            TOUT* cRow = C + row * ldc + col0 + wc * 64 + l15;
            #pragma unroll
            for (int n = 0; n < 4; ++n)
                store_out(cRow + n * 16, acc[m][n][r]);
        }
    }
}

extern "C" void kernel_launch(void* const* d_in, const int* in_sizes, int n_in,
                              void* d_out, int out_size, void* d_ws, size_t ws_size,
                              hipStream_t stream) {
    const float* hidden_f = (const float*)d_in[0];  // 16384 x 4096 f32
    const float* VT_f     = (const float*)d_in[1];  // 2048 x 4096 f32 (N,K)
    const float* U_f      = (const float*)d_in[2];  // 8 x 512 x 256 f32
    float* out = (float*)d_out;                     // 16384 x 4096 f32

    const long nHid = 16384L * 4096L;
    const long nVT  = 2048L * 4096L;
    const long nU   = 8L * 512L * 256L;
    const long nLat = 16384L * 2048L;

    ushort *hid_b, *vt_b, *u_b, *lat_b;
    const size_t needA = (size_t)(nHid + nVT + nU + nLat) * 2;
    if (ws_size >= needA) {
        ushort* w = (ushort*)d_ws;
        hid_b = w;  vt_b = hid_b + nHid;  u_b = vt_b + nVT;  lat_b = u_b + nU;
    } else {
        ushort* w = (ushort*)d_ws;
        lat_b = w;  u_b = lat_b + nLat;
        ushort* o = (ushort*)d_out;       // staged in d_out; fully overwritten by GEMM2
        hid_b = o;  vt_b = hid_b + nHid;
    }

    dim3 cblk(256, 1, 1);
    f32_to_bf16_kernel<<<dim3(2048), cblk, 0, stream>>>(hidden_f, hid_b, nHid / 8);
    f32_to_bf16_kernel<<<dim3(1024), cblk, 0, stream>>>(VT_f, vt_b, nVT / 8);
    f32_to_bf16_kernel<<<dim3(256),  cblk, 0, stream>>>(U_f,  u_b,  nU / 8);

    // GEMM1: latent[16384 x 2048] = hid * VT^T  (256^2 8-phase, 128 KiB LDS)
    hipFuncSetAttribute((const void*)gemm256_bf16<4096, 4096, 2048, 4096>,
                        hipFuncAttributeMaxDynamicSharedMemorySize, 131072);
    gemm256_bf16<4096, 4096, 2048, 4096><<<dim3(512), dim3(512), 131072, stream>>>(
        hid_b, vt_b, lat_b);

    // GEMM2 (block-diag): out[:, g*512:+512] = latent[:, g*256:+256] * U[g]^T
    dim3 g2(512 / 128, 16384 / 128, 8);
    gemm_bt_kernel<float><<<g2, dim3(256), 0, stream>>>(lat_b, u_b, out,
                                                        2048, 256, 4096, 256,
                                                        256L, 512L * 256L, 512L);
}

// Round 6
// 1870.078 us; speedup vs baseline: 1.0299x; 1.0299x over previous
//
#include <hip/hip_runtime.h>
#include <stdint.h>

// HeadwiseLowRankModule: out = blockdiag-GEMM(GEMM(hidden, VT^T), U^T), f32 I/O.
// Inputs converted to bf16 once. GEMM1: 256x256-tile 8-phase deep pipeline
// (T2 swizzle + counted vmcnt + setprio). Anti-spill round: per-phase B frags
// (no cross-phase b0/b1 caching), STATIC 128KiB LDS so RA sees the occupancy
// bound, amdgpu_waves_per_eu(1,2). GEMM2: proven m97 128x128 kernel.

typedef short  bf16x8  __attribute__((ext_vector_type(8)));
typedef float  f32x4   __attribute__((ext_vector_type(4)));
typedef ushort ushort8 __attribute__((ext_vector_type(8)));
typedef float  flt4    __attribute__((ext_vector_type(4)));

__device__ __forceinline__ void gload_lds16(const ushort* g, ushort* l) {
    __builtin_amdgcn_global_load_lds(
        (const __attribute__((address_space(1))) uint32_t*)g,
        (__attribute__((address_space(3))) uint32_t*)l, 16, 0, 0);
}

__device__ __forceinline__ ushort f2bf(float f) {
    union { float f; uint32_t u; } c; c.f = f;
    uint32_t u = c.u;
    uint32_t r = (u + 0x7FFFu + ((u >> 16) & 1u)) >> 16;  // RNE
    return (ushort)r;
}

__device__ __forceinline__ void cfence() { asm volatile("" ::: "memory"); }

template<int N> __device__ __forceinline__ void vwait() {
    if constexpr (N == 8)      asm volatile("s_waitcnt vmcnt(8)" ::: "memory");
    else if constexpr (N == 4) asm volatile("s_waitcnt vmcnt(4)" ::: "memory");
    else if constexpr (N == 2) asm volatile("s_waitcnt vmcnt(2)" ::: "memory");
    else if constexpr (N == 0) asm volatile("s_waitcnt vmcnt(0)" ::: "memory");
    // N < 0: no wait
}

// ---- f32 -> bf16 conversion ----
__global__ __launch_bounds__(256) void f32_to_bf16_kernel(
    const float* __restrict__ in, ushort* __restrict__ out, long n8)
{
    const long stride = (long)gridDim.x * blockDim.x;
    for (long i = (long)blockIdx.x * blockDim.x + threadIdx.x; i < n8; i += stride) {
        flt4 a = ((const flt4*)in)[2 * i];
        flt4 b = ((const flt4*)in)[2 * i + 1];
        ushort8 o;
        o[0] = f2bf(a[0]); o[1] = f2bf(a[1]); o[2] = f2bf(a[2]); o[3] = f2bf(a[3]);
        o[4] = f2bf(b[0]); o[5] = f2bf(b[1]); o[6] = f2bf(b[2]); o[7] = f2bf(b[3]);
        ((ushort8*)out)[i] = o;
    }
}

// =====================================================================
// GEMM1: 256x256 tile, BK=64, 8 waves (2Mx4N), 8-phase pipeline.
// Regions: R1=A rows[0,128), R3=A[128,256), R2=B[0,128), R4=B[128,256).
// Tile t phases (mg,ng)=(0,0),(0,1),(1,0),(1,1).
// Stage stream: R1(x)@4x, R2@4x+1, R4@4x+2, R3@4x+3.
// Tile t: p0 stages R4(t+1)->other, p1 R3(t+1)->other, p2 R1(t+2)->cur,
// p3 R2(t+2)->cur. Uniform vmcnt(8); tail drains 4 -> 2 -> 0.
// Swizzle: byteOff ^= (row&7)<<4. B frags re-read per phase (VGPR relief).
// =====================================================================

#define ARD(BUF, MG, MF, KK) \
    (*(const bf16x8*)&(BUF)[(((MG)*128 + wr*64 + (MF)*16 + l15) * 64) + \
                            (((((KK)<<2) | lq) ^ l7) << 3)])
#define BRD(BUF, NG, NF, KK) \
    (*(const bf16x8*)&(BUF)[(((NG)*128 + wc*32 + (NF)*16 + l15) * 64) + \
                            (((((KK)<<2) | lq) ^ l7) << 3)])

#define RD_A(BUF, MG) \
    _Pragma("unroll") \
    for (int mf = 0; mf < 4; ++mf) { a[mf][0] = ARD(BUF,MG,mf,0); a[mf][1] = ARD(BUF,MG,mf,1); }
#define RD_B(BUF, NG) \
    _Pragma("unroll") \
    for (int nf = 0; nf < 2; ++nf) { b[nf][0] = BRD(BUF,NG,nf,0); b[nf][1] = BRD(BUF,NG,nf,1); }

#define STAGE_A(H, KT, ABUF) do { \
    const ushort* _g = aSt + (H)*128*LDA + (KT)*64; \
    gload_lds16(_g,            (ABUF) + (H)*8192 + ldsoff0); \
    gload_lds16(_g + 64*LDA,   (ABUF) + (H)*8192 + ldsoff1); \
} while (0)
#define STAGE_B(H, KT, BBUF) do { \
    const ushort* _g = bSt + (H)*128*LDB + (KT)*64; \
    gload_lds16(_g,            (BBUF) + (H)*8192 + ldsoff0); \
    gload_lds16(_g + 64*LDB,   (BBUF) + (H)*8192 + ldsoff1); \
} while (0)

#define MFMA_Q(MG, NG) \
    _Pragma("unroll") \
    for (int mf = 0; mf < 4; ++mf) \
    _Pragma("unroll") \
    for (int nf = 0; nf < 2; ++nf) \
    _Pragma("unroll") \
    for (int kk = 0; kk < 2; ++kk) \
        acc[(MG)*4+mf][(NG)*2+nf] = __builtin_amdgcn_mfma_f32_16x16x32_bf16( \
            a[mf][kk], b[nf][kk], acc[(MG)*4+mf][(NG)*2+nf], 0, 0, 0);

#define PH_TAIL(MG, NG, W) \
    __builtin_amdgcn_s_barrier(); \
    __builtin_amdgcn_s_setprio(1); \
    MFMA_Q(MG, NG); \
    __builtin_amdgcn_s_setprio(0); \
    vwait<W>(); \
    __builtin_amdgcn_s_barrier(); \
    cfence();

#define TILE_BODY(CA, CB, OA, OB, KT1, KT2, S0, S1, S2, S3, W0, W1, W2, W3) do { \
    /* p0: read A mg0 + B ng0; stage R4(KT1)->other B */ \
    RD_A(CA, 0); RD_B(CB, 0); \
    if (S0) { STAGE_B(1, KT1, OB); } \
    PH_TAIL(0, 0, W0) \
    /* p1: read B ng1; stage R3(KT1)->other A */ \
    RD_B(CB, 1); \
    if (S1) { STAGE_A(1, KT1, OA); } \
    PH_TAIL(0, 1, W1) \
    /* p2: read A mg1 + B ng0 (re-read); stage R1(KT2)->cur A (free after p0) */ \
    RD_A(CA, 1); RD_B(CB, 0); \
    if (S2) { STAGE_A(0, KT2, CA); } \
    PH_TAIL(1, 0, W2) \
    /* p3: read B ng1 (re-read); stage R2(KT2)->cur B (free after p0) */ \
    RD_B(CB, 1); \
    if (S3) { STAGE_B(0, KT2, CB); } \
    PH_TAIL(1, 1, W3) \
} while (0)

template<int LDA, int LDB, int LDC, int KDIM>
__global__ __launch_bounds__(512)
__attribute__((amdgpu_waves_per_eu(1, 2)))
void gemm256_bf16(
    const ushort* __restrict__ A, const ushort* __restrict__ B,
    ushort* __restrict__ C)
{
    __shared__ ushort lds[65536];  // 128 KiB static: RA sees 1 wg/CU occupancy
    ushort* A0 = lds;              // buf0 A: 256x64 elems (32 KiB)
    ushort* B0 = lds + 16384;
    ushort* A1 = lds + 32768;
    ushort* B1 = lds + 49152;

    const int tid  = threadIdx.x;
    const int lane = tid & 63;
    const int wave = tid >> 6;       // 0..7
    const int wr = wave >> 2;        // 0..1
    const int wc = wave & 3;         // 0..3

    // XCD-locality mapping: x (N-tile) fastest -> each XCD keeps one VT panel
    const int bx = blockIdx.x & 7;
    const int by = blockIdx.x >> 3;
    const int row0 = by * 256;
    const int col0 = bx * 256;

    const int l15 = lane & 15;
    const int lq  = lane >> 4;       // 0..3
    const int l7  = lane & 7;

    // staging constants: linear idx = j*512 + tid; row = idx>>3; chunk swizzle
    const int srow = tid >> 3;                              // j=0 row (j=1: +64)
    const int scsw = (((tid & 7) ^ (srow & 7)) << 3);       // swizzled col (elems)
    const int ldsoff0 = (wave * 64) * 8;                    // wave-uniform dests
    const int ldsoff1 = (512 + wave * 64) * 8;

    // hoisted per-thread global staging bases
    const ushort* aSt = A + (size_t)(row0 + srow) * LDA + scsw;
    const ushort* bSt = B + (size_t)(col0 + srow) * LDB + scsw;

    f32x4 acc[8][4] = {};
    bf16x8 a[4][2], b[2][2];

    constexpr int nkt = KDIM >> 6;

    // Prologue: stage R1(0),R2(0),R4(0),R3(0),R1(1),R2(1)
    STAGE_A(0, 0, A0);
    STAGE_B(0, 0, B0);
    STAGE_B(1, 0, B0);
    STAGE_A(1, 0, A0);
    STAGE_A(0, 1, A1);
    STAGE_B(0, 1, B1);
    vwait<8>();                       // R1(0),R2(0) complete
    __builtin_amdgcn_s_barrier();
    cfence();

    for (int t = 0; t < nkt - 2; ++t) {
        if ((t & 1) == 0) TILE_BODY(A0, B0, A1, B1, t+1, t+2, 1,1,1,1, 8,8,8,8);
        else              TILE_BODY(A1, B1, A0, B0, t+1, t+2, 1,1,1,1, 8,8,8,8);
    }
    {   // tail tile nkt-2: stage only R4/R3(nkt-1); drain to 4
        const int t = nkt - 2;
        if ((t & 1) == 0) TILE_BODY(A0, B0, A1, B1, t+1, 0, 1,1,0,0, 8,8,8,4);
        else              TILE_BODY(A1, B1, A0, B0, t+1, 0, 1,1,0,0, 8,8,8,4);
    }
    {   // tail tile nkt-1: no staging; drain 2 -> 0
        const int t = nkt - 1;
        if ((t & 1) == 0) TILE_BODY(A0, B0, A1, B1, 0, 0, 0,0,0,0, 2,0,-1,-1);
        else              TILE_BODY(A1, B1, A0, B0, 0, 0, 0,0,0,0, 2,0,-1,-1);
    }

    // Epilogue: C/D layout col = lane&15, row = (lane>>4)*4 + reg
    #pragma unroll
    for (int mg = 0; mg < 2; ++mg)
    #pragma unroll
    for (int mf = 0; mf < 4; ++mf) {
        const int rowb = row0 + mg*128 + wr*64 + mf*16 + lq*4;
        #pragma unroll
        for (int r = 0; r < 4; ++r) {
            ushort* crow = C + (size_t)(rowb + r) * LDC;
            #pragma unroll
            for (int ng = 0; ng < 2; ++ng)
            #pragma unroll
            for (int nf = 0; nf < 2; ++nf)
                crow[col0 + ng*128 + wc*32 + nf*16 + l15] =
                    f2bf(acc[mg*4+mf][ng*2+nf][r]);
        }
    }
}

// ---- store helpers ----
__device__ __forceinline__ void store_out(ushort* p, float v) { *p = f2bf(v); }
__device__ __forceinline__ void store_out(float*  p, float v) { *p = v; }

// GEMM2: proven m97-style 128x128 kernel (block-diagonal via blockIdx.z)
template <typename TOUT>
__global__ __launch_bounds__(256) void gemm_bt_kernel(
    const ushort* __restrict__ A,
    const ushort* __restrict__ B,
    TOUT* __restrict__ C,
    int lda, int ldb, int ldc, int K,
    long aOffZ, long bOffZ, long cOffZ)
{
    A += (size_t)blockIdx.z * aOffZ;
    B += (size_t)blockIdx.z * bOffZ;
    C += (size_t)blockIdx.z * cOffZ;

    __shared__ ushort As[128 * 64];
    __shared__ ushort Bs[128 * 64];

    const int tid  = threadIdx.x;
    const int lane = tid & 63;
    const int wave = tid >> 6;

    const int row0 = blockIdx.y * 128;
    const int col0 = blockIdx.x * 128;

    const int wr = wave >> 1;
    const int wc = wave & 1;

    const int l15    = lane & 15;
    const int lq     = lane >> 4;
    const int lrow   = lane >> 3;
    const int lchunk = lane & 7;

    f32x4 acc[4][4] = {};

    const ushort* aPtr = A + (size_t)(row0 + wave * 32 + lrow) * lda + lchunk * 8;
    const ushort* bPtr = B + (size_t)(col0 + wave * 32 + lrow) * ldb + lchunk * 8;

    const int nkt = K / 64;
    for (int kt = 0; kt < nkt; ++kt) {
        const int kOff = kt * 64;
        __syncthreads();
        #pragma unroll
        for (int i = 0; i < 4; ++i) {
            gload_lds16(aPtr + (size_t)i * 8 * lda + kOff, As + (wave * 4 + i) * 512);
            gload_lds16(bPtr + (size_t)i * 8 * ldb + kOff, Bs + (wave * 4 + i) * 512);
        }
        __syncthreads();

        #pragma unroll
        for (int kk = 0; kk < 2; ++kk) {
            bf16x8 af[4], bfr[4];
            #pragma unroll
            for (int m = 0; m < 4; ++m)
                af[m] = *(const bf16x8*)&As[(wr * 64 + m * 16 + l15) * 64 + kk * 32 + lq * 8];
            #pragma unroll
            for (int n = 0; n < 4; ++n)
                bfr[n] = *(const bf16x8*)&Bs[(wc * 64 + n * 16 + l15) * 64 + kk * 32 + lq * 8];
            #pragma unroll
            for (int m = 0; m < 4; ++m)
                #pragma unroll
                for (int n = 0; n < 4; ++n)
                    acc[m][n] = __builtin_amdgcn_mfma_f32_16x16x32_bf16(
                        af[m], bfr[n], acc[m][n], 0, 0, 0);
        }
    }

    #pragma unroll
    for (int m = 0; m < 4; ++m) {
        #pragma unroll
        for (int r = 0; r < 4; ++r) {
            const size_t row = (size_t)(row0 + wr * 64 + m * 16 + lq * 4 + r);
            TOUT* cRow = C + row * ldc + col0 + wc * 64 + l15;
            #pragma unroll
            for (int n = 0; n < 4; ++n)
                store_out(cRow + n * 16, acc[m][n][r]);
        }
    }
}

extern "C" void kernel_launch(void* const* d_in, const int* in_sizes, int n_in,
                              void* d_out, int out_size, void* d_ws, size_t ws_size,
                              hipStream_t stream) {
    const float* hidden_f = (const float*)d_in[0];  // 16384 x 4096 f32
    const float* VT_f     = (const float*)d_in[1];  // 2048 x 4096 f32 (N,K)
    const float* U_f      = (const float*)d_in[2];  // 8 x 512 x 256 f32
    float* out = (float*)d_out;                     // 16384 x 4096 f32

    const long nHid = 16384L * 4096L;
    const long nVT  = 2048L * 4096L;
    const long nU   = 8L * 512L * 256L;
    const long nLat = 16384L * 2048L;

    ushort *hid_b, *vt_b, *u_b, *lat_b;
    const size_t needA = (size_t)(nHid + nVT + nU + nLat) * 2;
    if (ws_size >= needA) {
        ushort* w = (ushort*)d_ws;
        hid_b = w;  vt_b = hid_b + nHid;  u_b = vt_b + nVT;  lat_b = u_b + nU;
    } else {
        ushort* w = (ushort*)d_ws;
        lat_b = w;  u_b = lat_b + nLat;
        ushort* o = (ushort*)d_out;       // staged in d_out; fully overwritten by GEMM2
        hid_b = o;  vt_b = hid_b + nHid;
    }

    dim3 cblk(256, 1, 1);
    f32_to_bf16_kernel<<<dim3(2048), cblk, 0, stream>>>(hidden_f, hid_b, nHid / 8);
    f32_to_bf16_kernel<<<dim3(1024), cblk, 0, stream>>>(VT_f, vt_b, nVT / 8);
    f32_to_bf16_kernel<<<dim3(256),  cblk, 0, stream>>>(U_f,  u_b,  nU / 8);

    // GEMM1: latent[16384 x 2048] = hid * VT^T  (256^2 8-phase, static LDS)
    gemm256_bf16<4096, 4096, 2048, 4096><<<dim3(512), dim3(512), 0, stream>>>(
        hid_b, vt_b, lat_b);

    // GEMM2 (block-diag): out[:, g*512:+512] = latent[:, g*256:+256] * U[g]^T
    dim3 g2(512 / 128, 16384 / 128, 8);
    gemm_bt_kernel<float><<<g2, dim3(256), 0, stream>>>(lat_b, u_b, out,
                                                        2048, 256, 4096, 256,
                                                        256L, 512L * 256L, 512L);
}